// Round 1
// baseline (134.743 us; speedup 1.0000x reference)
//
#include <hip/hip_runtime.h>
#include <hip/hip_bf16.h>

using f32x4   = __attribute__((ext_vector_type(4))) float;
using short8  = __attribute__((ext_vector_type(8))) short;
using short4v = __attribute__((ext_vector_type(4))) short;

#define LOG_2PI 1.8378770664093453f

__device__ __forceinline__ short bf16bits(float x) {
  unsigned u = __builtin_bit_cast(unsigned, x);
  u = (u + 0x7FFFu + ((u >> 16) & 1u)) >> 16;   // RNE; inputs are finite
  return (short)u;
}

// Kernel 0: per (b,h) Gaussian params: center c, q = 0.5/var, base = -0.5*(log2pi+log var)
__global__ void prep_kernel(const float* __restrict__ dur,
                            const float* __restrict__ vars,
                            float* __restrict__ cA, float* __restrict__ qA,
                            float* __restrict__ bA, int H) {
  const int b = blockIdx.x;
  const int l = threadIdx.x;
  float run = 0.f;
  for (int h0 = 0; h0 < H; h0 += 64) {
    const int h = h0 + l;
    const float d = (h < H) ? dur[(size_t)b * H + h] : 0.f;
    float x = d;
#pragma unroll
    for (int off = 1; off < 64; off <<= 1) {
      float y = __shfl_up(x, off);
      if (l >= off) x += y;
    }
    if (h < H) {
      const float v = vars[(size_t)b * H + h];
      cA[(size_t)b * H + h] = run + x - 0.5f * d;
      qA[(size_t)b * H + h] = 0.5f / v;
      bA[(size_t)b * H + h] = -0.5f * (LOG_2PI + logf(v));
    }
    run += __shfl(x, 63);
  }
}

// Main fused kernel: one block = (batch b, 64-frame tile). 512 threads = 8 waves.
// Wave w owns output columns d in [64w, 64w+64). M=64 frames, K-chunks of 32 phonemes.
__launch_bounds__(512, 1)
__global__ void gup_kernel(const float* __restrict__ enc,
                           const float* __restrict__ cA,
                           const float* __restrict__ qA,
                           const float* __restrict__ bA,
                           const int* __restrict__ lens,
                           float* __restrict__ out,
                           int H, int T) {
  constexpr int D  = 512;
  constexpr int HP = 608;   // padded param storage
  constexpr int AS = 40;    // LDS row stride in halves (80B) for A and Et

  __shared__ float sc[HP], sq[HP], sb[HP];
  __shared__ float sm[64];
  __shared__ float sden[64];
  __shared__ short sA[64 * AS];     // weights tile [t][k]
  __shared__ short sE[512 * AS];    // enc tile transposed [d][k]

  const int tid = threadIdx.x;
  const int b   = blockIdx.y;
  const int t0  = blockIdx.x * 64;
  const int L   = lens[b];

  // phase 0: params -> LDS (zero-padded to HP)
  for (int i = tid; i < HP; i += 512) {
    const bool ok = i < H;
    sc[i] = ok ? cA[(size_t)b * H + i] : 0.f;
    sq[i] = ok ? qA[(size_t)b * H + i] : 0.f;
    sb[i] = ok ? bA[(size_t)b * H + i] : 0.f;
  }
  __syncthreads();

  // phase 1: per-frame max score over valid h  (8 lanes per frame)
  {
    const int f  = tid >> 3;
    const int hs = tid & 7;
    const float t = (float)(t0 + f);
    float m = -1e30f;
    for (int h = hs; h < L; h += 8) {
      const float d = t - sc[h];
      const float s = fmaf(-d * d, sq[h], sb[h]);
      m = fmaxf(m, s);
    }
#pragma unroll
    for (int off = 1; off < 8; off <<= 1) m = fmaxf(m, __shfl_xor(m, off));
    if ((tid & 7) == 0) sm[f] = m;
  }
  __syncthreads();

  const int lane = tid & 63;
  const int wv   = tid >> 6;
  const int l15  = lane & 15;
  const int lq   = lane >> 4;

  f32x4 acc[4][4];
#pragma unroll
  for (int i = 0; i < 4; ++i)
#pragma unroll
    for (int j = 0; j < 4; ++j) acc[i][j] = (f32x4){0.f, 0.f, 0.f, 0.f};

  // per-thread A-build assignment: frame tfA, 4 consecutive k at k4
  const int tfA = tid >> 3;
  const int k4  = (tid & 7) * 4;
  const float tA = (float)(t0 + tfA);
  const float mA = sm[tfA];
  float denAcc = 0.f;

  const float* encB = enc + (size_t)b * H * D + tid;  // this thread's d-column
  const int nChunks = (L + 31) >> 5;

  for (int cc = 0; cc < nChunks; ++cc) {
    const int h0 = cc * 32;

    // A tile: unnormalized weights p = exp(score - m), bf16
    {
      float p[4];
#pragma unroll
      for (int j = 0; j < 4; ++j) {
        const int h = h0 + k4 + j;
        const float d = tA - sc[h];
        const float s = fmaf(-d * d, sq[h], sb[h]);
        float pv = __expf(s - mA);
        pv = (h < L) ? pv : 0.f;
        p[j] = pv;
      }
      denAcc += (p[0] + p[1]) + (p[2] + p[3]);
      short4v w;
#pragma unroll
      for (int j = 0; j < 4; ++j) w[j] = bf16bits(p[j]);
      *(short4v*)&sA[tfA * AS + k4] = w;
    }

    // E tile: enc[h0+k][d] -> Et[d][k] bf16, one d-column per thread
    {
#pragma unroll
      for (int g = 0; g < 4; ++g) {
        const int hb = h0 + g * 8;
        float v[8];
#pragma unroll
        for (int j = 0; j < 8; ++j)
          v[j] = (hb + j < H) ? encB[(size_t)(hb + j) * D] : 0.f;
        short8 e;
#pragma unroll
        for (int j = 0; j < 8; ++j) e[j] = bf16bits(v[j]);
        *(short8*)&sE[tid * AS + g * 8] = e;
      }
    }
    __syncthreads();

    // MFMA: 4 m-tiles x 4 n-tiles of 16x16x32
    short8 af[4], bf[4];
#pragma unroll
    for (int mt = 0; mt < 4; ++mt)
      af[mt] = *(short8*)&sA[(mt * 16 + l15) * AS + lq * 8];
#pragma unroll
    for (int nt = 0; nt < 4; ++nt)
      bf[nt] = *(short8*)&sE[(wv * 64 + nt * 16 + l15) * AS + lq * 8];
#pragma unroll
    for (int mt = 0; mt < 4; ++mt)
#pragma unroll
      for (int nt = 0; nt < 4; ++nt)
        acc[mt][nt] = __builtin_amdgcn_mfma_f32_16x16x32_bf16(af[mt], bf[nt], acc[mt][nt], 0, 0, 0);
    __syncthreads();
  }

  // denominators: reduce the 8 threads sharing a frame
  {
    float dsum = denAcc;
#pragma unroll
    for (int off = 1; off < 8; off <<= 1) dsum += __shfl_xor(dsum, off);
    if ((tid & 7) == 0) sden[tfA] = dsum;
  }
  __syncthreads();

  // epilogue: normalize and store
#pragma unroll
  for (int mt = 0; mt < 4; ++mt) {
#pragma unroll
    for (int i = 0; i < 4; ++i) {
      const int tr = mt * 16 + lq * 4 + i;
      const int tg = t0 + tr;
      if (tg < T) {
        const float inv = 1.0f / sden[tr];
#pragma unroll
        for (int nt = 0; nt < 4; ++nt) {
          const int dc = wv * 64 + nt * 16 + l15;
          out[((size_t)b * T + tg) * D + dc] = acc[mt][nt][i] * inv;
        }
      }
    }
  }
}

extern "C" void kernel_launch(void* const* d_in, const int* in_sizes, int n_in,
                              void* d_out, int out_size, void* d_ws, size_t ws_size,
                              hipStream_t stream) {
  const float* enc  = (const float*)d_in[0];
  const float* dur  = (const float*)d_in[1];
  const float* vars = (const float*)d_in[2];
  const int*   lens = (const int*)d_in[3];

  const int B = in_sizes[3];
  const int H = in_sizes[1] / B;
  const int D = in_sizes[0] / in_sizes[1];
  const int T = out_size / (B * D);
  (void)D; (void)n_in; (void)ws_size;

  float* cA = (float*)d_ws;
  float* qA = cA + (size_t)B * H;
  float* bA = qA + (size_t)B * H;

  prep_kernel<<<B, 64, 0, stream>>>(dur, vars, cA, qA, bA, H);

  dim3 grid((T + 63) / 64, B);
  gup_kernel<<<grid, 512, 0, stream>>>(enc, cA, qA, bA, lens, (float*)d_out, H, T);
}

// Round 2
// 99.874 us; speedup vs baseline: 1.3491x; 1.3491x over previous
//
#include <hip/hip_runtime.h>
#include <hip/hip_bf16.h>

using f32x4   = __attribute__((ext_vector_type(4))) float;
using short8  = __attribute__((ext_vector_type(8))) short;
using short4v = __attribute__((ext_vector_type(4))) short;

#define LOG_2PI 1.8378770664093453f
#define HP2 608   // padded phoneme axis for bf16 transposed enc and params

__device__ __forceinline__ short bf16bits(float x) {
  unsigned u = __builtin_bit_cast(unsigned, x);
  u = (u + 0x7FFFu + ((u >> 16) & 1u)) >> 16;   // RNE; inputs are finite
  return (short)u;
}
__device__ __forceinline__ float bf16round(float x) {
  unsigned u = __builtin_bit_cast(unsigned, x);
  u = ((u + 0x7FFFu + ((u >> 16) & 1u)) >> 16) << 16;
  return __builtin_bit_cast(float, u);
}

// Kernel 0: per (b,h) Gaussian params: center c, q = 0.5/var, base = -0.5*(log2pi+log var)
__global__ void prep_kernel(const float* __restrict__ dur,
                            const float* __restrict__ vars,
                            float* __restrict__ cA, float* __restrict__ qA,
                            float* __restrict__ bA, int H) {
  const int b = blockIdx.x;
  const int l = threadIdx.x;
  float run = 0.f;
  for (int h0 = 0; h0 < H; h0 += 64) {
    const int h = h0 + l;
    const float d = (h < H) ? dur[(size_t)b * H + h] : 0.f;
    float x = d;
#pragma unroll
    for (int off = 1; off < 64; off <<= 1) {
      float y = __shfl_up(x, off);
      if (l >= off) x += y;
    }
    if (h < H) {
      const float v = vars[(size_t)b * H + h];
      cA[(size_t)b * H + h] = run + x - 0.5f * d;
      qA[(size_t)b * H + h] = 0.5f / v;
      bA[(size_t)b * H + h] = -0.5f * (LOG_2PI + logf(v));
    }
    run += __shfl(x, 63);
  }
}

// Kernel 1: enc [B][H][D] f32  ->  encT [B][D][HP2] bf16 (h >= H zero-padded).
// 64h x 64d tiles through LDS; 256 threads.
__global__ void transpose_kernel(const float* __restrict__ enc,
                                 short* __restrict__ encT,
                                 int H, int D) {
  __shared__ short sT[64][66];     // 66-short row stride -> conflict-free
  const int b  = blockIdx.z;
  const int h0 = blockIdx.y * 64;
  const int d0 = blockIdx.x * 64;
  const int tid = threadIdx.x;
  const int tx = tid & 63;         // d within tile
  const int ty = tid >> 6;         // 0..3

  const float* ebase = enc + (size_t)b * H * D + d0 + tx;
#pragma unroll
  for (int i = 0; i < 16; ++i) {
    const int h = h0 + ty + i * 4;
    const float v = (h < H) ? ebase[(size_t)h * D] : 0.f;
    sT[tx][ty + i * 4] = bf16bits(v);
  }
  __syncthreads();

  const int tx4 = (tid & 15) * 4;  // h within tile (4 consecutive)
  const int ty2 = tid >> 4;        // 0..15 (d)
  if (h0 + tx4 < HP2) {
#pragma unroll
    for (int i = 0; i < 4; ++i) {
      const int d = d0 + ty2 + i * 16;
      short4v v;
#pragma unroll
      for (int j = 0; j < 4; ++j) v[j] = sT[ty2 + i * 16][tx4 + j];
      *(short4v*)&encT[((size_t)b * D + d) * HP2 + h0 + tx4] = v;
    }
  }
}

// Main fused kernel: one block = (batch b, 64-frame tile). 512 threads = 8 waves.
// Wave w owns output columns d in [64w, 64w+64). K-chunks of 32 phonemes.
// B-fragments come straight from global encT (L2-resident); only the weight
// tile sA goes through LDS (double-buffered, 1 barrier per chunk).
__launch_bounds__(512, 1)
__global__ void gup_kernel(const short* __restrict__ encT,
                           const float* __restrict__ cA,
                           const float* __restrict__ qA,
                           const float* __restrict__ bA,
                           const int* __restrict__ lens,
                           float* __restrict__ out,
                           int H, int T) {
  constexpr int D  = 512;
  constexpr int AS = 40;           // sA row stride in halves (80B)

  __shared__ float sc[HP2], sq[HP2], sb[HP2];
  __shared__ float sm[64];
  __shared__ float sden[64];
  __shared__ short sA[2][64 * AS]; // weights tile [t][k], double-buffered

  const int tid = threadIdx.x;
  const int b   = blockIdx.y;
  const int t0  = blockIdx.x * 64;
  const int L   = lens[b];

  // phase 0: params -> LDS (zero-padded to HP2)
  for (int i = tid; i < HP2; i += 512) {
    const bool ok = i < H;
    sc[i] = ok ? cA[(size_t)b * H + i] : 0.f;
    sq[i] = ok ? qA[(size_t)b * H + i] : 0.f;
    sb[i] = ok ? bA[(size_t)b * H + i] : 0.f;
  }
  __syncthreads();

  // phase 1: per-frame max score over valid h (8 lanes per frame)
  {
    const int f  = tid >> 3;
    const int hs = tid & 7;
    const float t = (float)(t0 + f);
    float m = -1e30f;
    for (int h = hs; h < L; h += 8) {
      const float d = t - sc[h];
      const float s = fmaf(-d * d, sq[h], sb[h]);
      m = fmaxf(m, s);
    }
#pragma unroll
    for (int off = 1; off < 8; off <<= 1) m = fmaxf(m, __shfl_xor(m, off));
    if ((tid & 7) == 0) sm[f] = m;
  }
  __syncthreads();

  const int lane = tid & 63;
  const int wv   = tid >> 6;
  const int l15  = lane & 15;
  const int lq   = lane >> 4;

  f32x4 acc[4][4];
#pragma unroll
  for (int i = 0; i < 4; ++i)
#pragma unroll
    for (int j = 0; j < 4; ++j) acc[i][j] = (f32x4){0.f, 0.f, 0.f, 0.f};

  // per-thread A-build assignment: frame tfA, 4 consecutive k at k4
  const int tfA = tid >> 3;
  const int k4  = (tid & 7) * 4;
  const float tA = (float)(t0 + tfA);
  const float mA = sm[tfA];
  float denAcc = 0.f;

  // this lane's B-fragment base: row d = wv*64 + nt*16 + l15, col chunk h0 + lq*8
  const short* bp = encT + ((size_t)b * D + wv * 64 + l15) * HP2 + lq * 8;

  const int nChunks = (L + 31) >> 5;
  int p = 0;

  for (int cc = 0; cc < nChunks; ++cc, p ^= 1) {
    const int h0 = cc * 32;

    // A tile: unnormalized weights w = exp(score - m), bf16 (RNE to match MFMA input)
    {
      short4v w;
#pragma unroll
      for (int j = 0; j < 4; ++j) {
        const int h = h0 + k4 + j;
        const float d = tA - sc[h];
        const float s = fmaf(-d * d, sq[h], sb[h]);
        float pv = __expf(s - mA);
        pv = (h < L) ? pv : 0.f;
        w[j] = bf16bits(pv);
        denAcc += bf16round(pv);   // denominator from the rounded weights
      }
      *(short4v*)&sA[p][tfA * AS + k4] = w;
    }
    __syncthreads();

    short8 af[4], bf[4];
#pragma unroll
    for (int mt = 0; mt < 4; ++mt)
      af[mt] = *(short8*)&sA[p][(mt * 16 + l15) * AS + lq * 8];
#pragma unroll
    for (int nt = 0; nt < 4; ++nt)
      bf[nt] = *(const short8*)(bp + (size_t)nt * 16 * HP2 + h0);
#pragma unroll
    for (int mt = 0; mt < 4; ++mt)
#pragma unroll
      for (int nt = 0; nt < 4; ++nt)
        acc[mt][nt] = __builtin_amdgcn_mfma_f32_16x16x32_bf16(af[mt], bf[nt], acc[mt][nt], 0, 0, 0);
    // no second barrier: next iteration writes the other sA buffer; the next
    // barrier orders re-use of this one.
  }

  // denominators: reduce the 8 threads sharing a frame
  {
    float dsum = denAcc;
#pragma unroll
    for (int off = 1; off < 8; off <<= 1) dsum += __shfl_xor(dsum, off);
    if ((tid & 7) == 0) sden[tfA] = dsum;
  }
  __syncthreads();

  // epilogue: normalize and store
#pragma unroll
  for (int mt = 0; mt < 4; ++mt) {
#pragma unroll
    for (int i = 0; i < 4; ++i) {
      const int tr = mt * 16 + lq * 4 + i;
      const int tg = t0 + tr;
      if (tg < T) {
        const float inv = 1.0f / sden[tr];
#pragma unroll
        for (int nt = 0; nt < 4; ++nt) {
          const int dc = wv * 64 + nt * 16 + l15;
          out[((size_t)b * T + tg) * D + dc] = acc[mt][nt][i] * inv;
        }
      }
    }
  }
}

extern "C" void kernel_launch(void* const* d_in, const int* in_sizes, int n_in,
                              void* d_out, int out_size, void* d_ws, size_t ws_size,
                              hipStream_t stream) {
  const float* enc  = (const float*)d_in[0];
  const float* dur  = (const float*)d_in[1];
  const float* vars = (const float*)d_in[2];
  const int*   lens = (const int*)d_in[3];

  const int B = in_sizes[3];
  const int H = in_sizes[1] / B;
  const int D = in_sizes[0] / in_sizes[1];
  const int T = out_size / (B * D);
  (void)n_in; (void)ws_size;

  float* cA = (float*)d_ws;
  float* qA = cA + (size_t)B * H;
  float* bA = qA + (size_t)B * H;
  short* encT = (short*)(bA + (size_t)B * H);   // B*D*HP2 bf16 ≈ 20 MB

  prep_kernel<<<B, 64, 0, stream>>>(dur, vars, cA, qA, bA, H);

  dim3 tgrid(D / 64, (HP2 + 63) / 64, B);
  transpose_kernel<<<tgrid, 256, 0, stream>>>(enc, encT, H, D);

  dim3 grid((T + 63) / 64, B);
  gup_kernel<<<grid, 512, 0, stream>>>(encT, cA, qA, bA, lens, (float*)d_out, H, T);
}